// Round 9
// baseline (564.678 us; speedup 1.0000x reference)
//
#include <hip/hip_runtime.h>

// ---------------------------------------------------------------------------
// GATv2 (2 layers) + mean-pool + MLP for MI355X.
// N=50000 nodes, E=800000 edges (+N self loops), IN=128, HID=64, HEADS=2,
// OUT=3, 64 graphs. Output: [64,3] float32.
// R1: k_agg2 pool atomic storm fixed (LDS pre-reduction). 1128 -> 803 us.
// R2: CSR + per-node online softmax; edge phases fused.   803 -> 515 us.
// R3: fused1 2-edge ILP + reg src cache + W2-proj fused.   515 -> 394 us.
// R4: fused1 2 nodes/wave + 4-edge ILP + batched softmax.  394 -> 368 us.
// R5: gemm 128x128 reg-blocked (LDS 72KB->16KB).            368 -> 343 us.
// R6: DPP rotate-reduce + exp2 domain; gemm 64x128/4x8.     343 -> 337 us.
// R7: 8-edge unroll flat. R8-R10: degree-sort detour regressed; reverted.
// R11: 3-phase parallel scan (single-block scan was 100us!). 422 -> 329 us.
// R12: xl1 message table bf16 (gather 512->256B/edge).       329 -> 326 us.
// R13: k_fill atomic-free; gemm merged (x@W1l AND x@W1r).    326 -> 282 us.
// R14: GEMM to matrix cores via split-bf16 (hh+hl+lh).       282 -> 277 us.
// R15/16: frag-order pre-pack; 1KB coalesced frag loads.     277 -> 259 us.
// R17: fused1 packed-f16 logit (fdot2); fused2 4 lanes/node. 259 -> 245 us.
// R18: fused1 8-edge FAILED (padding + wave skew). REVERTED.
// R19: GEMM HBM round-trip killed (x staged to LDS in-kernel). 245 -> 239 us.
// R20: fused1 sw-pipeline NEUTRAL; scan_top folded. 239 -> 237 us.
// R21: visibility round: top-5 revealed the harness's 256MiB workspace
//      re-poison fill (~44us/iter, harness-side, not ours). Split/merge
//      net-neutral (~2us per dispatch). Kernels <44us now invisible.
// R22: k_fused1 persistent waves + work-stealing. Occupancy was 60% with
//      VGPR=32/no-LDS (static limit 100%): block retires at max of its 4
//      waves' degrees + grid tail = drain waste. Now 2048 resident blocks;
//      each WAVE pulls pairs from a global atomic ticket (lane0 + shfl).
//      Half-split reverted (moot). Math/order unchanged -> bit-identical.
// ---------------------------------------------------------------------------

#define NGRAPH 64
#define LOG2E 1.4426950408889634f

typedef __attribute__((ext_vector_type(2))) _Float16 hf2;

// v_mov_dpp row_ror:k (16-lane rows). Valid reduce permutation for
// commutative ops; leaves every lane of the row with the full result.
#define DPP_ROR(C, x) \
  __int_as_float(__builtin_amdgcn_update_dpp(0, __float_as_int(x), (0x120 | C), 0xF, 0xF, false))
// quad_perm DPP (ctrl 0x00-0xFF): rotate within 4-lane quads.
#define DPP_QUAD(C, x) \
  __int_as_float(__builtin_amdgcn_update_dpp(0, __float_as_int(x), (C), 0xF, 0xF, false))

__device__ __forceinline__ float rowsum16(float v) {
  v += DPP_ROR(8, v);
  v += DPP_ROR(4, v);
  v += DPP_ROR(2, v);
  v += DPP_ROR(1, v);
  return v;
}

__device__ __forceinline__ unsigned bf16rne(float f) {
  unsigned u = __float_as_uint(f);
  return (u + 0x7FFFu + ((u >> 16) & 1u)) >> 16;
}

__device__ __forceinline__ unsigned short f16u(float f) {
  union { _Float16 h; unsigned short u; } v;
  v.h = (_Float16)f;  // v_cvt_f16_f32, RNE
  return v.u;
}

__device__ __forceinline__ hf2 as_hf2(unsigned u) {
  union { unsigned u; hf2 h; } v;
  v.u = u;
  return v.h;
}

typedef __attribute__((ext_vector_type(8))) short bf16x8;
typedef __attribute__((ext_vector_type(4))) float f32x4;

// ---------------------------------------------------------------------------
// R21 merged: blocks [0,degb) = k_deg (atomic return IS the edge's rank);
// blocks [degb,degb+16) = W-pack (split-bf16, MFMA frag order).
__global__ __launch_bounds__(256) void k_prep(const int* __restrict__ ei, int E, int Et,
                                              int* __restrict__ deg,
                                              int* __restrict__ rank,
                                              const float* __restrict__ W1l,
                                              const float* __restrict__ W1r,
                                              unsigned short* __restrict__ whp,
                                              unsigned short* __restrict__ wlp,
                                              int degb) {
  if ((int)blockIdx.x >= degb) {
    // --- W-pack: slot ((colblk*4+kc)*64+l)*8+j holds
    // W[kc*32+(l>>4)*8+j][colblk*16+(l&15)]; cols 0..127=W1l, 128..255=W1r.
    int t = threadIdx.x;
    int kc = t >> 6;
    int l = t & 63;
    int lr = l & 15;
    int k0 = kc * 32 + ((l >> 4) << 3);
    int b = (int)blockIdx.x - degb;  // 0..15
    int col = b * 16 + lr;
    float f[8];
#pragma unroll
    for (int j = 0; j < 8; ++j)
      f[j] = (col < 128) ? W1l[(size_t)(k0 + j) * 128 + col]
                         : W1r[(size_t)(k0 + j) * 128 + (col - 128)];
    unsigned hv[8], lv[8];
#pragma unroll
    for (int j = 0; j < 8; ++j) {
      hv[j] = bf16rne(f[j]);
      float r = f[j] - __uint_as_float(hv[j] << 16);
      lv[j] = bf16rne(r);
    }
    uint4 ph, pl;
    ph.x = hv[0] | (hv[1] << 16); ph.y = hv[2] | (hv[3] << 16);
    ph.z = hv[4] | (hv[5] << 16); ph.w = hv[6] | (hv[7] << 16);
    pl.x = lv[0] | (lv[1] << 16); pl.y = lv[2] | (lv[3] << 16);
    pl.z = lv[4] | (lv[5] << 16); pl.w = lv[6] | (lv[7] << 16);
    size_t slot = (((size_t)b * 4 + kc) * 64 + l) * 8;
    *(uint4*)&whp[slot] = ph;
    *(uint4*)&wlp[slot] = pl;
    return;
  }
  int e = blockIdx.x * 256 + threadIdx.x;
  if (e >= Et) return;
  int d = (e < E) ? ei[E + e] : (e - E);  // dst only
  rank[e] = atomicAdd(&deg[d], 1);        // coalesced store of the rank
}

// ---------------------------------------------------------------------------
// Parallel exclusive scan of deg[0..n) -> row_ptr[0..n]. Top-level prefix
// computed inside k_scan_write by a 64-lane shuffle reduce (R20).
__global__ __launch_bounds__(256) void k_scan_part(const int* __restrict__ deg,
                                                   int* __restrict__ bsum, int n) {
  __shared__ int sd[256];
  int t = threadIdx.x;
  int i = blockIdx.x * 1024 + t * 4;
  int s = 0;
  if (i + 4 <= n) {
    int4 d = *(const int4*)&deg[i];
    s = d.x + d.y + d.z + d.w;
  } else {
    for (int j = i; j < min(i + 4, n); ++j) s += deg[j];
  }
  sd[t] = s;
  __syncthreads();
  for (int off = 128; off; off >>= 1) {
    if (t < off) sd[t] += sd[t + off];
    __syncthreads();
  }
  if (t == 0) bsum[blockIdx.x] = sd[0];
}

__global__ __launch_bounds__(256) void k_scan_write(const int* __restrict__ deg,
                                                    const int* __restrict__ bsum,
                                                    int* __restrict__ row_ptr,
                                                    int n, int nb) {
  __shared__ int sd[256];
  __shared__ int boff;
  int t = threadIdx.x;
  if (t < 64) {
    int v = (t < nb && t < (int)blockIdx.x) ? bsum[t] : 0;
#pragma unroll
    for (int off = 32; off; off >>= 1) v += __shfl_xor(v, off);
    if (t == 0) boff = v;
  }
  int i = blockIdx.x * 1024 + t * 4;
  int4 d = make_int4(0, 0, 0, 0);
  bool full = (i + 4 <= n);
  if (full) d = *(const int4*)&deg[i];
  else {
    if (i + 0 < n) d.x = deg[i + 0];
    if (i + 1 < n) d.y = deg[i + 1];
    if (i + 2 < n) d.z = deg[i + 2];
    if (i + 3 < n) d.w = deg[i + 3];
  }
  int s = d.x + d.y + d.z + d.w;
  sd[t] = s;
  __syncthreads();
  for (int off = 1; off < 256; off <<= 1) {  // Hillis-Steele inclusive
    int v = (t >= off) ? sd[t - off] : 0;
    __syncthreads();
    sd[t] += v;
    __syncthreads();
  }
  int ex = sd[t] - s + boff;
  int4 r;
  r.x = ex;
  r.y = ex + d.x;
  r.z = r.y + d.y;
  r.w = r.z + d.z;
  if (full) {
    *(int4*)&row_ptr[i] = r;
    if (i + 4 == n) row_ptr[n] = r.w + d.w;
  } else if (i < n) {
    int run = ex;
    int vals[4] = {d.x, d.y, d.z, d.w};
    for (int j = 0; j < 4 && i + j < n; ++j) {
      row_ptr[i + j] = run;
      run += vals[j];
    }
    if (i <= n && i + 4 > n) row_ptr[n] = run;
  }
}

// ---------------------------------------------------------------------------
// R21 merged: blocks [0,gmb) = matrix-core GEMM (R19: x staged to LDS in
// frag order, split-bf16 hi/lo, 3 MFMA passes -> bit-identical fp32-class);
// blocks [gmb,..) = k_fill (atomic-free CSR scatter; latency overlaps MFMA).
__global__ __launch_bounds__(256) void k_gmfill(const float* __restrict__ x,
                                                const unsigned short* __restrict__ whp,
                                                const unsigned short* __restrict__ wlp,
                                                unsigned short* __restrict__ outl,
                                                unsigned short* __restrict__ outr,
                                                int n, int gmb,
                                                const int* __restrict__ ei, int E, int Et,
                                                const int* __restrict__ row_ptr,
                                                const int* __restrict__ rank,
                                                int* __restrict__ csr_src) {
  __shared__ __align__(16) unsigned short xh_lds[2 * 4 * 64 * 8];  // 8KB
  __shared__ __align__(16) unsigned short xl_lds[2 * 4 * 64 * 8];  // 8KB
  if ((int)blockIdx.x >= gmb) {
    // --- k_fill: slot is row_ptr[d] + precomputed rank (no atomics).
    int e = ((int)blockIdx.x - gmb) * 256 + threadIdx.x;
    if (e >= Et) return;
    int s, d;
    if (e < E) { s = ei[e]; d = ei[E + e]; }
    else       { s = e - E; d = s; }
    csr_src[row_ptr[d] + rank[e]] = s;
    return;
  }
  int t = threadIdx.x;
  int skc = t >> 6;               // staging k-chunk 0..3
  int sl = t & 63;
  int slr = sl & 15;
  int sk0 = skc * 32 + ((sl >> 4) << 3);
  int r0 = blockIdx.x * 32;

#pragma unroll
  for (int rb = 0; rb < 2; ++rb) {
    int row = r0 + rb * 16 + slr;
    float f[8];
    if (row < n) {
      float4 a = *(const float4*)&x[(size_t)row * 128 + sk0];
      float4 c = *(const float4*)&x[(size_t)row * 128 + sk0 + 4];
      f[0] = a.x; f[1] = a.y; f[2] = a.z; f[3] = a.w;
      f[4] = c.x; f[5] = c.y; f[6] = c.z; f[7] = c.w;
    } else {
#pragma unroll
      for (int j = 0; j < 8; ++j) f[j] = 0.f;
    }
    unsigned hv[8], lv[8];
#pragma unroll
    for (int j = 0; j < 8; ++j) {
      hv[j] = bf16rne(f[j]);
      float r = f[j] - __uint_as_float(hv[j] << 16);
      lv[j] = bf16rne(r);
    }
    uint4 ph, pl;
    ph.x = hv[0] | (hv[1] << 16); ph.y = hv[2] | (hv[3] << 16);
    ph.z = hv[4] | (hv[5] << 16); ph.w = hv[6] | (hv[7] << 16);
    pl.x = lv[0] | (lv[1] << 16); pl.y = lv[2] | (lv[3] << 16);
    pl.z = lv[4] | (lv[5] << 16); pl.w = lv[6] | (lv[7] << 16);
    int slot = ((rb * 4 + skc) * 64 + sl) * 8;
    *(uint4*)&xh_lds[slot] = ph;
    *(uint4*)&xl_lds[slot] = pl;
  }
  __syncthreads();

  int w = t >> 6;
  int lane = t & 63;
  int lr = lane & 15;

  f32x4 acc[2][4] = {};

#pragma unroll
  for (int kc = 0; kc < 4; ++kc) {
    bf16x8 ah[2], al[2], bh[4], bl[4];
#pragma unroll
    for (int m = 0; m < 2; ++m) {
      int slot = ((m * 4 + kc) * 64 + lane) * 8;
      ah[m] = *(const bf16x8*)&xh_lds[slot];
      al[m] = *(const bf16x8*)&xl_lds[slot];
    }
#pragma unroll
    for (int f = 0; f < 4; ++f) {
      size_t slot = (((size_t)(w * 4 + f) * 4 + kc) * 64 + lane) * 8;
      bh[f] = *(const bf16x8*)&whp[slot];
      bl[f] = *(const bf16x8*)&wlp[slot];
    }
#pragma unroll
    for (int m = 0; m < 2; ++m)
#pragma unroll
      for (int f = 0; f < 4; ++f) {
        acc[m][f] = __builtin_amdgcn_mfma_f32_16x16x32_bf16(ah[m], bh[f], acc[m][f], 0, 0, 0);
        acc[m][f] = __builtin_amdgcn_mfma_f32_16x16x32_bf16(ah[m], bl[f], acc[m][f], 0, 0, 0);
        acc[m][f] = __builtin_amdgcn_mfma_f32_16x16x32_bf16(al[m], bh[f], acc[m][f], 0, 0, 0);
      }
  }

  int rbase = (lane >> 4) * 4;
  unsigned short* dst = (w < 2) ? outl : outr;
  int cb = (w & 1) * 64;
#pragma unroll
  for (int m = 0; m < 2; ++m)
#pragma unroll
    for (int f = 0; f < 4; ++f) {
      int col = cb + f * 16 + lr;
#pragma unroll
      for (int i = 0; i < 4; ++i) {
        int row = r0 + m * 16 + rbase + i;
        if (row < n)
          dst[(size_t)row * 128 + col] = f16u(acc[m][f][i]);
      }
    }
}

// ---------------------------------------------------------------------------
// fused layer-1 edge phase + layer-2 input projection.
// R22: PERSISTENT WAVES + WORK-STEALING. 2048 resident blocks; each wave
// pulls a node-pair index from the global ticket (lane0 atomicAdd + shfl).
// Within a pair: lanes 0-31 = node 2w, 32-63 = node 2w+1; lane holds 4
// channels; 16-lane head groups = DPP rows; 4 edges/iter, pipelined (R20).
// Math identical to R20 -> bit-identical output.
__global__ __launch_bounds__(256) void k_fused1(const unsigned short* __restrict__ xl,
                                                const unsigned short* __restrict__ xr,
                                                const int* __restrict__ row_ptr,
                                                const int* __restrict__ csr_src,
                                                const float* __restrict__ att1,
                                                const float* __restrict__ b1,
                                                const float* __restrict__ W2l,
                                                const float* __restrict__ W2r,
                                                float* __restrict__ xl2,
                                                float* __restrict__ xr2,
                                                int n, int npairs,
                                                int* __restrict__ ticket) {
  int lane = threadIdx.x & 63;
  int half = lane >> 5;
  int sub  = lane & 31;
  int ch = sub * 4;
  const char* xlb = (const char*)xl;
  unsigned chb = (unsigned)sub * 8u;  // byte offset within 256B f16 row

  // pair-invariant constants
  float4 atv = *(const float4*)&att1[ch];
  hf2 at01, at23;
  at01.x = (_Float16)(atv.x * LOG2E); at01.y = (_Float16)(atv.y * LOG2E);
  at23.x = (_Float16)(atv.z * LOG2E); at23.y = (_Float16)(atv.w * LOG2E);
  hf2 k02; k02.x = (_Float16)0.2f; k02.y = (_Float16)0.2f;
  float4 b1v = *(const float4*)&b1[ch];
  float4 u0 = *(const float4*)&W2l[ch * 3 + 0];
  float4 u1 = *(const float4*)&W2l[ch * 3 + 4];
  float4 u2 = *(const float4*)&W2l[ch * 3 + 8];
  float4 v0 = *(const float4*)&W2r[ch * 3 + 0];
  float4 v1 = *(const float4*)&W2r[ch * 3 + 4];
  float4 v2 = *(const float4*)&W2r[ch * 3 + 8];

// per-edge: packed-f16 logit + f32 message recovery
#define EDGE(p, x0, x1, x2, x3, q)                                      \
    { hf2 v01 = as_hf2(q.x), v23 = as_hf2(q.y);                         \
      hf2 t01 = v01 + xr01, t23 = v23 + xr23;                           \
      hf2 l01 = __builtin_elementwise_max(t01, t01 * k02);              \
      hf2 l23 = __builtin_elementwise_max(t23, t23 * k02);              \
      p = __builtin_amdgcn_fdot2(l23, at23,                             \
            __builtin_amdgcn_fdot2(l01, at01, 0.f, false), false);      \
      x0 = (float)v01.x; x1 = (float)v01.y;                             \
      x2 = (float)v23.x; x3 = (float)v23.y; }

  for (;;) {
    int wid;
    if (lane == 0) wid = atomicAdd(ticket, 1);
    wid = __shfl(wid, 0);
    if (wid >= npairs) break;

    int node = min(wid * 2 + half, n - 1);  // dup of last node is benign
    uint2 xrq = *(const uint2*)&xr[(size_t)node * 128 + ch];
    hf2 xr01 = as_hf2(xrq.x), xr23 = as_hf2(xrq.y);

    int s0 = row_ptr[node];
    int deg = row_ptr[node + 1] - s0;  // >=1 (self-loop)
    int odeg = __shfl_xor(deg, 32);
    int maxdeg = max(deg, odeg);  // wave-uniform
    int dm1 = deg - 1;
    const int* sp = csr_src + s0;

    float m = -1e30f, l = 0.f;
    float4 acc = make_float4(0.f, 0.f, 0.f, 0.f);

    // prologue gathers for e = 0..3 (clamped -> always in-bounds)
    uint2 q0, q1, q2, q3;
    {
      int sA = sp[0];
      int sB = sp[min(1, dm1)];
      int sC = sp[min(2, dm1)];
      int sD = sp[min(3, dm1)];
      q0 = *(const uint2*)(xlb + (((unsigned)sA << 8) + chb));
      q1 = *(const uint2*)(xlb + (((unsigned)sB << 8) + chb));
      q2 = *(const uint2*)(xlb + (((unsigned)sC << 8) + chb));
      q3 = *(const uint2*)(xlb + (((unsigned)sD << 8) + chb));
    }

    for (int e = 0; e < maxdeg; e += 4) {
      int en = e + 4;
      int sA = sp[min(en + 0, dm1)];
      int sB = sp[min(en + 1, dm1)];
      int sC = sp[min(en + 2, dm1)];
      int sD = sp[min(en + 3, dm1)];
      uint2 f0 = *(const uint2*)(xlb + (((unsigned)sA << 8) + chb));
      uint2 f1 = *(const uint2*)(xlb + (((unsigned)sB << 8) + chb));
      uint2 f2 = *(const uint2*)(xlb + (((unsigned)sC << 8) + chb));
      uint2 f3 = *(const uint2*)(xlb + (((unsigned)sD << 8) + chb));

      float pa, pb, pc, pd;
      float xa0, xa1, xa2, xa3, xb0, xb1, xb2, xb3;
      float xc0, xc1, xc2, xc3, xd0, xd1, xd2, xd3;
      EDGE(pa, xa0, xa1, xa2, xa3, q0)
      EDGE(pb, xb0, xb1, xb2, xb3, q1)
      EDGE(pc, xc0, xc1, xc2, xc3, q2)
      EDGE(pd, xd0, xd1, xd2, xd3, q3)
      pa = rowsum16(pa);
      pb = rowsum16(pb);
      pc = rowsum16(pc);
      pd = rowsum16(pd);
      pa = (e + 0 < deg) ? pa : -1e30f;
      pb = (e + 1 < deg) ? pb : -1e30f;
      pc = (e + 2 < deg) ? pc : -1e30f;
      pd = (e + 3 < deg) ? pd : -1e30f;
      float mn = fmaxf(m, fmaxf(fmaxf(pa, pb), fmaxf(pc, pd)));
      float sc = exp2f(m - mn);
      float wa = exp2f(pa - mn);
      float wb = exp2f(pb - mn);
      float wc = exp2f(pc - mn);
      float wd = exp2f(pd - mn);
      acc.x = fmaf(wd, xd0, fmaf(wc, xc0, fmaf(wb, xb0, fmaf(wa, xa0, acc.x * sc))));
      acc.y = fmaf(wd, xd1, fmaf(wc, xc1, fmaf(wb, xb1, fmaf(wa, xa1, acc.y * sc))));
      acc.z = fmaf(wd, xd2, fmaf(wc, xc2, fmaf(wb, xb2, fmaf(wa, xa2, acc.z * sc))));
      acc.w = fmaf(wd, xd3, fmaf(wc, xc3, fmaf(wb, xb3, fmaf(wa, xa3, acc.w * sc))));
      l = fmaf(l, sc, wa + wb + wc + wd);
      m = mn;

      q0 = f0; q1 = f1; q2 = f2; q3 = f3;
    }

    float inv = 1.f / (l + 1e-16f);
    float4 h;
    h.x = acc.x * inv + b1v.x; h.x = h.x > 0.f ? h.x : expm1f(h.x);
    h.y = acc.y * inv + b1v.y; h.y = h.y > 0.f ? h.y : expm1f(h.y);
    h.z = acc.z * inv + b1v.z; h.z = h.z > 0.f ? h.z : expm1f(h.z);
    h.w = acc.w * inv + b1v.w; h.w = h.w > 0.f ? h.w : expm1f(h.w);

    float al0 = fmaf(h.w, u2.y, fmaf(h.z, u1.z, fmaf(h.y, u0.w, h.x * u0.x)));
    float al1 = fmaf(h.w, u2.z, fmaf(h.z, u1.w, fmaf(h.y, u1.x, h.x * u0.y)));
    float al2 = fmaf(h.w, u2.w, fmaf(h.z, u2.x, fmaf(h.y, u1.y, h.x * u0.z)));
    float ar0 = fmaf(h.w, v2.y, fmaf(h.z, v1.z, fmaf(h.y, v0.w, h.x * v0.x)));
    float ar1 = fmaf(h.w, v2.z, fmaf(h.z, v1.w, fmaf(h.y, v1.x, h.x * v0.y)));
    float ar2 = fmaf(h.w, v2.w, fmaf(h.z, v2.x, fmaf(h.y, v1.y, h.x * v0.z)));
#pragma unroll
    for (int off = 1; off < 32; off <<= 1) {
      al0 += __shfl_xor(al0, off); al1 += __shfl_xor(al1, off);
      al2 += __shfl_xor(al2, off); ar0 += __shfl_xor(ar0, off);
      ar1 += __shfl_xor(ar1, off); ar2 += __shfl_xor(ar2, off);
    }
    if (sub == 0 && wid * 2 + half < n) {
      *(float4*)&xl2[node * 4] = make_float4(al0, al1, al2, 0.f);
      *(float4*)&xr2[node * 4] = make_float4(ar0, ar1, ar2, 0.f);
    }
  }
#undef EDGE
}

// ---------------------------------------------------------------------------
// fused layer-2 edge phase + mean-pool. FOUR lanes per node (16 nodes per
// wave); quad_perm rotate-merge x2. Pool pre-reduced in LDS.
__global__ __launch_bounds__(256) void k_fused2(const float* __restrict__ xl2,
                                                const float* __restrict__ xr2,
                                                const int* __restrict__ row_ptr,
                                                const int* __restrict__ csr_src,
                                                const float* __restrict__ att2,
                                                const float* __restrict__ b2,
                                                const int* __restrict__ batch,
                                                float* __restrict__ gsum,
                                                float* __restrict__ gcnt, int n) {
  __shared__ float ls[NGRAPH * 3];
  __shared__ float lc[NGRAPH];
  int t = threadIdx.x;
  for (int i = t; i < NGRAPH * 3; i += 256) ls[i] = 0.f;
  for (int i = t; i < NGRAPH; i += 256) lc[i] = 0.f;
  __syncthreads();

  int node = (blockIdx.x * 256 + t) >> 2;  // 64 nodes per block
  int lane = t & 3;
  if (node < n) {
    float4 xrv = *(const float4*)&xr2[node * 4];
    float c0 = att2[0] * LOG2E, c1 = att2[1] * LOG2E, c2 = att2[2] * LOG2E;
    int s0 = row_ptr[node], s1 = row_ptr[node + 1];
    float m = -1e30f, l = 0.f, a0 = 0.f, a1 = 0.f, a2 = 0.f;
    for (int slot = s0 + lane; slot < s1; slot += 4) {
      int s = csr_src[slot];
      float4 xlv = *(const float4*)&xl2[s * 4];
      float t0 = xlv.x + xrv.x; t0 = fmaxf(t0, 0.2f * t0);
      float t1 = xlv.y + xrv.y; t1 = fmaxf(t1, 0.2f * t1);
      float t2 = xlv.z + xrv.z; t2 = fmaxf(t2, 0.2f * t2);
      float p = fmaf(t2, c2, fmaf(t1, c1, t0 * c0));
      float mn = fmaxf(m, p);
      float sc = exp2f(m - mn);
      float w  = exp2f(p - mn);
      a0 = a0 * sc + w * xlv.x;
      a1 = a1 * sc + w * xlv.y;
      a2 = a2 * sc + w * xlv.z;
      l = l * sc + w;
      m = mn;
    }
#define MERGEQ(C)                                                       \
    {                                                                   \
      float m2 = DPP_QUAD(C, m);                                        \
      float l2 = DPP_QUAD(C, l);                                        \
      float b0 = DPP_QUAD(C, a0);                                       \
      float b1v = DPP_QUAD(C, a1);                                      \
      float b2v = DPP_QUAD(C, a2);                                      \
      float mn = fmaxf(m, m2);                                          \
      float sA = exp2f(m - mn);                                         \
      float sB = exp2f(m2 - mn);                                        \
      a0 = a0 * sA + b0 * sB;                                           \
      a1 = a1 * sA + b1v * sB;                                          \
      a2 = a2 * sA + b2v * sB;                                          \
      l = l * sA + l2 * sB;                                             \
      m = mn;                                                           \
    }
    MERGEQ(0x39) MERGEQ(0x4E)
#undef MERGEQ
    if (lane == 0) {
      float inv = 1.f / (l + 1e-16f);
      float o0 = a0 * inv + b2[0];
      float o1 = a1 * inv + b2[1];
      float o2 = a2 * inv + b2[2];
      int b = batch[node];
      atomicAdd(&ls[b * 3 + 0], o0);
      atomicAdd(&ls[b * 3 + 1], o1);
      atomicAdd(&ls[b * 3 + 2], o2);
      atomicAdd(&lc[b], 1.f);
    }
  }
  __syncthreads();
  for (int i = t; i < NGRAPH * 3; i += 256)
    if (ls[i] != 0.f) atomicAdd(&gsum[i], ls[i]);
  for (int i = t; i < NGRAPH; i += 256)
    if (lc[i] != 0.f) atomicAdd(&gcnt[i], lc[i]);
}

// 1 block, 64 threads: per-graph mean + 2-layer MLP
__global__ __launch_bounds__(64) void k_mlp(const float* __restrict__ gsum,
                                            const float* __restrict__ gcnt,
                                            const float* __restrict__ Wr1,
                                            const float* __restrict__ br1,
                                            const float* __restrict__ Wr2,
                                            const float* __restrict__ br2,
                                            float* __restrict__ out) {
  int t = threadIdx.x;
  if (t >= NGRAPH) return;
  float cnt = fmaxf(gcnt[t], 1.f);
  float g0 = gsum[t * 3 + 0] / cnt;
  float g1 = gsum[t * 3 + 1] / cnt;
  float g2 = gsum[t * 3 + 2] / cnt;
  float o0 = br2[0], o1 = br2[1], o2 = br2[2];
  for (int j = 0; j < 64; ++j) {
    float hj = g0 * Wr1[j] + g1 * Wr1[64 + j] + g2 * Wr1[128 + j] + br1[j];
    hj = fmaxf(hj, 0.f);
    o0 = fmaf(hj, Wr2[j * 3 + 0], o0);
    o1 = fmaf(hj, Wr2[j * 3 + 1], o1);
    o2 = fmaf(hj, Wr2[j * 3 + 2], o2);
  }
  out[t * 3 + 0] = o0;
  out[t * 3 + 1] = o1;
  out[t * 3 + 2] = o2;
}

// ---------------------------------------------------------------------------
extern "C" void kernel_launch(void* const* d_in, const int* in_sizes, int n_in,
                              void* d_out, int out_size, void* d_ws, size_t ws_size,
                              hipStream_t stream) {
  const float* x    = (const float*)d_in[0];
  const int*   ei   = (const int*)d_in[1];
  const int*   batch= (const int*)d_in[2];
  const float* W1l  = (const float*)d_in[3];
  const float* W1r  = (const float*)d_in[4];
  const float* att1 = (const float*)d_in[5];
  const float* b1   = (const float*)d_in[6];
  const float* W2l  = (const float*)d_in[7];
  const float* W2r  = (const float*)d_in[8];
  const float* att2 = (const float*)d_in[9];
  const float* b2   = (const float*)d_in[10];
  const float* Wr1  = (const float*)d_in[11];
  const float* br1  = (const float*)d_in[12];
  const float* Wr2  = (const float*)d_in[13];
  const float* br2  = (const float*)d_in[14];
  float* out = (float*)d_out;

  const int N  = in_sizes[0] / 128;
  const int E  = in_sizes[1] / 2;
  const int Et = E + N;
  const int NB = (N + 1023) / 1024;    // scan blocks (<=64)
  const int NB32 = (N + 31) / 32;      // gmfma blocks
  const int DEGB = (Et + 255) / 256;   // deg/fill blocks

  char* p = (char*)d_ws;
  auto alloc = [&](size_t bytes) -> char* {
    char* r = p;
    p += (bytes + 255) & ~(size_t)255;
    return r;
  };
  unsigned short* xl1 = (unsigned short*)alloc((size_t)N * 128 * 2);  // f16
  unsigned short* xr1 = (unsigned short*)alloc((size_t)N * 128 * 2);  // f16
  int*      row_ptr= (int*)alloc((size_t)(N + 1) * 4);
  int*      csr_src= (int*)alloc((size_t)Et * 4);
  int*      rank   = (int*)alloc((size_t)Et * 4);
  int*      bsum   = (int*)alloc(64 * 4);
  // zero-init group (one memset): deg | gsum | gcnt | ticket
  char*     z0     = p;
  int*      deg    = (int*)alloc((size_t)N * 4);
  float*    gsum   = (float*)alloc(NGRAPH * 3 * 4);
  float*    gcnt   = (float*)alloc(NGRAPH * 4);
  int*      ticket = (int*)alloc(4);
  size_t    zbytes = (size_t)(p - z0);
  float*    xl2    = (float*)alloc((size_t)N * 4 * 4);
  float*    xr2    = (float*)alloc((size_t)N * 4 * 4);
  unsigned short* whp = (unsigned short*)alloc((size_t)16 * 2048 * 2);
  unsigned short* wlp = (unsigned short*)alloc((size_t)16 * 2048 * 2);

  hipMemsetAsync(z0, 0, zbytes, stream);
  hipLaunchKernelGGL(k_prep, dim3(DEGB + 16), dim3(256), 0, stream,
                     ei, E, Et, deg, rank, W1l, W1r, whp, wlp, DEGB);
  hipLaunchKernelGGL(k_scan_part, dim3(NB), dim3(256), 0, stream, deg, bsum, N);
  hipLaunchKernelGGL(k_scan_write, dim3(NB), dim3(256), 0, stream,
                     deg, bsum, row_ptr, N, NB);
  hipLaunchKernelGGL(k_gmfill, dim3(NB32 + DEGB), dim3(256), 0, stream,
                     x, whp, wlp, xl1, xr1, N, NB32,
                     ei, E, Et, row_ptr, rank, csr_src);
  // R22: persistent work-stealing fused1 (2048 resident blocks)
  int npairs = (N + 1) / 2;
  hipLaunchKernelGGL(k_fused1, dim3(2048), dim3(256), 0, stream,
                     xl1, xr1, row_ptr, csr_src, att1, b1, W2l, W2r, xl2, xr2,
                     N, npairs, ticket);
  hipLaunchKernelGGL(k_fused2, dim3((N * 4 + 255) / 256), dim3(256), 0, stream,
                     xl2, xr2, row_ptr, csr_src, att2, b2, batch, gsum, gcnt, N);
  hipLaunchKernelGGL(k_mlp, dim3(1), dim3(64), 0, stream,
                     gsum, gcnt, Wr1, br1, Wr2, br2, out);
}

// Round 10
// 229.691 us; speedup vs baseline: 2.4584x; 2.4584x over previous
//
#include <hip/hip_runtime.h>

// ---------------------------------------------------------------------------
// GATv2 (2 layers) + mean-pool + MLP for MI355X.
// N=50000 nodes, E=800000 edges (+N self loops), IN=128, HID=64, HEADS=2,
// OUT=3, 64 graphs. Output: [64,3] float32.
// R1: k_agg2 pool atomic storm fixed (LDS pre-reduction). 1128 -> 803 us.
// R2: CSR + per-node online softmax; edge phases fused.   803 -> 515 us.
// R3: fused1 2-edge ILP + reg src cache + W2-proj fused.   515 -> 394 us.
// R4: fused1 2 nodes/wave + 4-edge ILP + batched softmax.  394 -> 368 us.
// R5: gemm 128x128 reg-blocked (LDS 72KB->16KB).            368 -> 343 us.
// R6: DPP rotate-reduce + exp2 domain; gemm 64x128/4x8.     343 -> 337 us.
// R7: 8-edge unroll flat. R8-R10: degree-sort detour regressed; reverted.
// R11: 3-phase parallel scan (single-block scan was 100us!). 422 -> 329 us.
// R12: xl1 message table bf16 (gather 512->256B/edge).       329 -> 326 us.
// R13: k_fill atomic-free; gemm merged (x@W1l AND x@W1r).    326 -> 282 us.
// R14: GEMM to matrix cores via split-bf16 (hh+hl+lh).       282 -> 277 us.
// R15/16: frag-order pre-pack; 1KB coalesced frag loads.     277 -> 259 us.
// R17: fused1 packed-f16 logit (fdot2); fused2 4 lanes/node. 259 -> 245 us.
// R18: fused1 8-edge FAILED (padding + wave skew). REVERTED.
// R19: GEMM HBM round-trip killed (x staged to LDS in-kernel). 245 -> 239 us.
// R20: fused1 sw-pipeline NEUTRAL; scan_top folded. 239 -> 237 us.
// R21: visibility round: top-5 revealed the harness's 256MiB re-poison fill
//      (~44us/iter, harness-side). Split/merge net-neutral.
// R22: fused1 work-stealing CATASTROPHIC (238 -> 565): ~25K per-wave tickets
//      on ONE cacheline; single-address atomic throughput ~15ns serialized
//      across XCDs = 375us dispenser, whole kernel queued behind it.
//      Occupancy-drain theory also disproven (persistent blocks still 43%).
// R23: REVERT to best verified config: R20's static pipelined fused1
//      (single dispatch) + R21's dispatch merges (k_prep, k_gmfill).
//      fused1 ~54us accepted as floor (4 structural attempts: flat/-9%/
//      flat/-7x). All numerics bit-identical to R20's passing run.
// ---------------------------------------------------------------------------

#define NGRAPH 64
#define LOG2E 1.4426950408889634f

typedef __attribute__((ext_vector_type(2))) _Float16 hf2;

// v_mov_dpp row_ror:k (16-lane rows). Valid reduce permutation for
// commutative ops; leaves every lane of the row with the full result.
#define DPP_ROR(C, x) \
  __int_as_float(__builtin_amdgcn_update_dpp(0, __float_as_int(x), (0x120 | C), 0xF, 0xF, false))
// quad_perm DPP (ctrl 0x00-0xFF): rotate within 4-lane quads.
#define DPP_QUAD(C, x) \
  __int_as_float(__builtin_amdgcn_update_dpp(0, __float_as_int(x), (C), 0xF, 0xF, false))

__device__ __forceinline__ float rowsum16(float v) {
  v += DPP_ROR(8, v);
  v += DPP_ROR(4, v);
  v += DPP_ROR(2, v);
  v += DPP_ROR(1, v);
  return v;
}

__device__ __forceinline__ unsigned bf16rne(float f) {
  unsigned u = __float_as_uint(f);
  return (u + 0x7FFFu + ((u >> 16) & 1u)) >> 16;
}

__device__ __forceinline__ unsigned short f16u(float f) {
  union { _Float16 h; unsigned short u; } v;
  v.h = (_Float16)f;  // v_cvt_f16_f32, RNE
  return v.u;
}

__device__ __forceinline__ hf2 as_hf2(unsigned u) {
  union { unsigned u; hf2 h; } v;
  v.u = u;
  return v.h;
}

typedef __attribute__((ext_vector_type(8))) short bf16x8;
typedef __attribute__((ext_vector_type(4))) float f32x4;

// ---------------------------------------------------------------------------
// R21 merged: blocks [0,degb) = k_deg (atomic return IS the edge's rank);
// blocks [degb,degb+16) = W-pack (split-bf16, MFMA frag order).
__global__ __launch_bounds__(256) void k_prep(const int* __restrict__ ei, int E, int Et,
                                              int* __restrict__ deg,
                                              int* __restrict__ rank,
                                              const float* __restrict__ W1l,
                                              const float* __restrict__ W1r,
                                              unsigned short* __restrict__ whp,
                                              unsigned short* __restrict__ wlp,
                                              int degb) {
  if ((int)blockIdx.x >= degb) {
    // --- W-pack: slot ((colblk*4+kc)*64+l)*8+j holds
    // W[kc*32+(l>>4)*8+j][colblk*16+(l&15)]; cols 0..127=W1l, 128..255=W1r.
    int t = threadIdx.x;
    int kc = t >> 6;
    int l = t & 63;
    int lr = l & 15;
    int k0 = kc * 32 + ((l >> 4) << 3);
    int b = (int)blockIdx.x - degb;  // 0..15
    int col = b * 16 + lr;
    float f[8];
#pragma unroll
    for (int j = 0; j < 8; ++j)
      f[j] = (col < 128) ? W1l[(size_t)(k0 + j) * 128 + col]
                         : W1r[(size_t)(k0 + j) * 128 + (col - 128)];
    unsigned hv[8], lv[8];
#pragma unroll
    for (int j = 0; j < 8; ++j) {
      hv[j] = bf16rne(f[j]);
      float r = f[j] - __uint_as_float(hv[j] << 16);
      lv[j] = bf16rne(r);
    }
    uint4 ph, pl;
    ph.x = hv[0] | (hv[1] << 16); ph.y = hv[2] | (hv[3] << 16);
    ph.z = hv[4] | (hv[5] << 16); ph.w = hv[6] | (hv[7] << 16);
    pl.x = lv[0] | (lv[1] << 16); pl.y = lv[2] | (lv[3] << 16);
    pl.z = lv[4] | (lv[5] << 16); pl.w = lv[6] | (lv[7] << 16);
    size_t slot = (((size_t)b * 4 + kc) * 64 + l) * 8;
    *(uint4*)&whp[slot] = ph;
    *(uint4*)&wlp[slot] = pl;
    return;
  }
  int e = blockIdx.x * 256 + threadIdx.x;
  if (e >= Et) return;
  int d = (e < E) ? ei[E + e] : (e - E);  // dst only
  rank[e] = atomicAdd(&deg[d], 1);        // coalesced store of the rank
}

// ---------------------------------------------------------------------------
// Parallel exclusive scan of deg[0..n) -> row_ptr[0..n]. Top-level prefix
// computed inside k_scan_write by a 64-lane shuffle reduce (R20).
__global__ __launch_bounds__(256) void k_scan_part(const int* __restrict__ deg,
                                                   int* __restrict__ bsum, int n) {
  __shared__ int sd[256];
  int t = threadIdx.x;
  int i = blockIdx.x * 1024 + t * 4;
  int s = 0;
  if (i + 4 <= n) {
    int4 d = *(const int4*)&deg[i];
    s = d.x + d.y + d.z + d.w;
  } else {
    for (int j = i; j < min(i + 4, n); ++j) s += deg[j];
  }
  sd[t] = s;
  __syncthreads();
  for (int off = 128; off; off >>= 1) {
    if (t < off) sd[t] += sd[t + off];
    __syncthreads();
  }
  if (t == 0) bsum[blockIdx.x] = sd[0];
}

__global__ __launch_bounds__(256) void k_scan_write(const int* __restrict__ deg,
                                                    const int* __restrict__ bsum,
                                                    int* __restrict__ row_ptr,
                                                    int n, int nb) {
  __shared__ int sd[256];
  __shared__ int boff;
  int t = threadIdx.x;
  if (t < 64) {
    int v = (t < nb && t < (int)blockIdx.x) ? bsum[t] : 0;
#pragma unroll
    for (int off = 32; off; off >>= 1) v += __shfl_xor(v, off);
    if (t == 0) boff = v;
  }
  int i = blockIdx.x * 1024 + t * 4;
  int4 d = make_int4(0, 0, 0, 0);
  bool full = (i + 4 <= n);
  if (full) d = *(const int4*)&deg[i];
  else {
    if (i + 0 < n) d.x = deg[i + 0];
    if (i + 1 < n) d.y = deg[i + 1];
    if (i + 2 < n) d.z = deg[i + 2];
    if (i + 3 < n) d.w = deg[i + 3];
  }
  int s = d.x + d.y + d.z + d.w;
  sd[t] = s;
  __syncthreads();
  for (int off = 1; off < 256; off <<= 1) {  // Hillis-Steele inclusive
    int v = (t >= off) ? sd[t - off] : 0;
    __syncthreads();
    sd[t] += v;
    __syncthreads();
  }
  int ex = sd[t] - s + boff;
  int4 r;
  r.x = ex;
  r.y = ex + d.x;
  r.z = r.y + d.y;
  r.w = r.z + d.z;
  if (full) {
    *(int4*)&row_ptr[i] = r;
    if (i + 4 == n) row_ptr[n] = r.w + d.w;
  } else if (i < n) {
    int run = ex;
    int vals[4] = {d.x, d.y, d.z, d.w};
    for (int j = 0; j < 4 && i + j < n; ++j) {
      row_ptr[i + j] = run;
      run += vals[j];
    }
    if (i <= n && i + 4 > n) row_ptr[n] = run;
  }
}

// ---------------------------------------------------------------------------
// R21 merged: blocks [0,gmb) = matrix-core GEMM (R19: x staged to LDS in
// frag order, split-bf16 hi/lo, 3 MFMA passes -> bit-identical fp32-class);
// blocks [gmb,..) = k_fill (atomic-free CSR scatter; latency overlaps MFMA).
__global__ __launch_bounds__(256) void k_gmfill(const float* __restrict__ x,
                                                const unsigned short* __restrict__ whp,
                                                const unsigned short* __restrict__ wlp,
                                                unsigned short* __restrict__ outl,
                                                unsigned short* __restrict__ outr,
                                                int n, int gmb,
                                                const int* __restrict__ ei, int E, int Et,
                                                const int* __restrict__ row_ptr,
                                                const int* __restrict__ rank,
                                                int* __restrict__ csr_src) {
  __shared__ __align__(16) unsigned short xh_lds[2 * 4 * 64 * 8];  // 8KB
  __shared__ __align__(16) unsigned short xl_lds[2 * 4 * 64 * 8];  // 8KB
  if ((int)blockIdx.x >= gmb) {
    // --- k_fill: slot is row_ptr[d] + precomputed rank (no atomics).
    int e = ((int)blockIdx.x - gmb) * 256 + threadIdx.x;
    if (e >= Et) return;
    int s, d;
    if (e < E) { s = ei[e]; d = ei[E + e]; }
    else       { s = e - E; d = s; }
    csr_src[row_ptr[d] + rank[e]] = s;
    return;
  }
  int t = threadIdx.x;
  int skc = t >> 6;               // staging k-chunk 0..3
  int sl = t & 63;
  int slr = sl & 15;
  int sk0 = skc * 32 + ((sl >> 4) << 3);
  int r0 = blockIdx.x * 32;

#pragma unroll
  for (int rb = 0; rb < 2; ++rb) {
    int row = r0 + rb * 16 + slr;
    float f[8];
    if (row < n) {
      float4 a = *(const float4*)&x[(size_t)row * 128 + sk0];
      float4 c = *(const float4*)&x[(size_t)row * 128 + sk0 + 4];
      f[0] = a.x; f[1] = a.y; f[2] = a.z; f[3] = a.w;
      f[4] = c.x; f[5] = c.y; f[6] = c.z; f[7] = c.w;
    } else {
#pragma unroll
      for (int j = 0; j < 8; ++j) f[j] = 0.f;
    }
    unsigned hv[8], lv[8];
#pragma unroll
    for (int j = 0; j < 8; ++j) {
      hv[j] = bf16rne(f[j]);
      float r = f[j] - __uint_as_float(hv[j] << 16);
      lv[j] = bf16rne(r);
    }
    uint4 ph, pl;
    ph.x = hv[0] | (hv[1] << 16); ph.y = hv[2] | (hv[3] << 16);
    ph.z = hv[4] | (hv[5] << 16); ph.w = hv[6] | (hv[7] << 16);
    pl.x = lv[0] | (lv[1] << 16); pl.y = lv[2] | (lv[3] << 16);
    pl.z = lv[4] | (lv[5] << 16); pl.w = lv[6] | (lv[7] << 16);
    int slot = ((rb * 4 + skc) * 64 + sl) * 8;
    *(uint4*)&xh_lds[slot] = ph;
    *(uint4*)&xl_lds[slot] = pl;
  }
  __syncthreads();

  int w = t >> 6;
  int lane = t & 63;
  int lr = lane & 15;

  f32x4 acc[2][4] = {};

#pragma unroll
  for (int kc = 0; kc < 4; ++kc) {
    bf16x8 ah[2], al[2], bh[4], bl[4];
#pragma unroll
    for (int m = 0; m < 2; ++m) {
      int slot = ((m * 4 + kc) * 64 + lane) * 8;
      ah[m] = *(const bf16x8*)&xh_lds[slot];
      al[m] = *(const bf16x8*)&xl_lds[slot];
    }
#pragma unroll
    for (int f = 0; f < 4; ++f) {
      size_t slot = (((size_t)(w * 4 + f) * 4 + kc) * 64 + lane) * 8;
      bh[f] = *(const bf16x8*)&whp[slot];
      bl[f] = *(const bf16x8*)&wlp[slot];
    }
#pragma unroll
    for (int m = 0; m < 2; ++m)
#pragma unroll
      for (int f = 0; f < 4; ++f) {
        acc[m][f] = __builtin_amdgcn_mfma_f32_16x16x32_bf16(ah[m], bh[f], acc[m][f], 0, 0, 0);
        acc[m][f] = __builtin_amdgcn_mfma_f32_16x16x32_bf16(ah[m], bl[f], acc[m][f], 0, 0, 0);
        acc[m][f] = __builtin_amdgcn_mfma_f32_16x16x32_bf16(al[m], bh[f], acc[m][f], 0, 0, 0);
      }
  }

  int rbase = (lane >> 4) * 4;
  unsigned short* dst = (w < 2) ? outl : outr;
  int cb = (w & 1) * 64;
#pragma unroll
  for (int m = 0; m < 2; ++m)
#pragma unroll
    for (int f = 0; f < 4; ++f) {
      int col = cb + f * 16 + lr;
#pragma unroll
      for (int i = 0; i < 4; ++i) {
        int row = r0 + m * 16 + rbase + i;
        if (row < n)
          dst[(size_t)row * 128 + col] = f16u(acc[m][f][i]);
      }
    }
}

// ---------------------------------------------------------------------------
// fused layer-1 edge phase + layer-2 input projection.
// TWO nodes per wave: lanes 0-31 = node 2w, 32-63 = node 2w+1. Lane holds 4
// channels; 16-lane head groups = DPP rows. 4 edges/iter, pipelined (R20):
// next iteration's 4 indices + 4 gathers issued before processing current 4.
// Unified always-clamped loop; masked edges add exactly +0.0 (bit-identical).
__global__ __launch_bounds__(256) void k_fused1(const unsigned short* __restrict__ xl,
                                                const unsigned short* __restrict__ xr,
                                                const int* __restrict__ row_ptr,
                                                const int* __restrict__ csr_src,
                                                const float* __restrict__ att1,
                                                const float* __restrict__ b1,
                                                const float* __restrict__ W2l,
                                                const float* __restrict__ W2r,
                                                float* __restrict__ xl2,
                                                float* __restrict__ xr2, int n) {
  int wid  = (blockIdx.x * 256 + threadIdx.x) >> 6;
  int lane = threadIdx.x & 63;
  int sub  = lane & 31;
  int node = min(wid * 2 + (lane >> 5), n - 1);  // dup of last node is benign
  int ch = sub * 4;
  const char* xlb = (const char*)xl;
  unsigned chb = (unsigned)sub * 8u;  // byte offset within 256B f16 row

  uint2 xrq = *(const uint2*)&xr[(size_t)node * 128 + ch];
  hf2 xr01 = as_hf2(xrq.x), xr23 = as_hf2(xrq.y);
  float4 atv = *(const float4*)&att1[ch];
  hf2 at01, at23;
  at01.x = (_Float16)(atv.x * LOG2E); at01.y = (_Float16)(atv.y * LOG2E);
  at23.x = (_Float16)(atv.z * LOG2E); at23.y = (_Float16)(atv.w * LOG2E);
  hf2 k02; k02.x = (_Float16)0.2f; k02.y = (_Float16)0.2f;

  int s0 = row_ptr[node];
  int deg = row_ptr[node + 1] - s0;  // >=1 (self-loop)
  int odeg = __shfl_xor(deg, 32);
  int maxdeg = max(deg, odeg);  // wave-uniform
  int dm1 = deg - 1;
  const int* sp = csr_src + s0;

  float m = -1e30f, l = 0.f;
  float4 acc = make_float4(0.f, 0.f, 0.f, 0.f);

// per-edge: packed-f16 logit + f32 message recovery
#define EDGE(p, x0, x1, x2, x3, q)                                      \
    { hf2 v01 = as_hf2(q.x), v23 = as_hf2(q.y);                         \
      hf2 t01 = v01 + xr01, t23 = v23 + xr23;                           \
      hf2 l01 = __builtin_elementwise_max(t01, t01 * k02);              \
      hf2 l23 = __builtin_elementwise_max(t23, t23 * k02);              \
      p = __builtin_amdgcn_fdot2(l23, at23,                             \
            __builtin_amdgcn_fdot2(l01, at01, 0.f, false), false);      \
      x0 = (float)v01.x; x1 = (float)v01.y;                             \
      x2 = (float)v23.x; x3 = (float)v23.y; }

  // prologue: gathers for e = 0..3 (clamped -> always in-bounds)
  uint2 q0, q1, q2, q3;
  {
    int sA = sp[0];
    int sB = sp[min(1, dm1)];
    int sC = sp[min(2, dm1)];
    int sD = sp[min(3, dm1)];
    q0 = *(const uint2*)(xlb + (((unsigned)sA << 8) + chb));
    q1 = *(const uint2*)(xlb + (((unsigned)sB << 8) + chb));
    q2 = *(const uint2*)(xlb + (((unsigned)sC << 8) + chb));
    q3 = *(const uint2*)(xlb + (((unsigned)sD << 8) + chb));
  }

  for (int e = 0; e < maxdeg; e += 4) {
    int en = e + 4;
    int sA = sp[min(en + 0, dm1)];
    int sB = sp[min(en + 1, dm1)];
    int sC = sp[min(en + 2, dm1)];
    int sD = sp[min(en + 3, dm1)];
    uint2 f0 = *(const uint2*)(xlb + (((unsigned)sA << 8) + chb));
    uint2 f1 = *(const uint2*)(xlb + (((unsigned)sB << 8) + chb));
    uint2 f2 = *(const uint2*)(xlb + (((unsigned)sC << 8) + chb));
    uint2 f3 = *(const uint2*)(xlb + (((unsigned)sD << 8) + chb));

    float pa, pb, pc, pd;
    float xa0, xa1, xa2, xa3, xb0, xb1, xb2, xb3;
    float xc0, xc1, xc2, xc3, xd0, xd1, xd2, xd3;
    EDGE(pa, xa0, xa1, xa2, xa3, q0)
    EDGE(pb, xb0, xb1, xb2, xb3, q1)
    EDGE(pc, xc0, xc1, xc2, xc3, q2)
    EDGE(pd, xd0, xd1, xd2, xd3, q3)
    pa = rowsum16(pa);
    pb = rowsum16(pb);
    pc = rowsum16(pc);
    pd = rowsum16(pd);
    pa = (e + 0 < deg) ? pa : -1e30f;
    pb = (e + 1 < deg) ? pb : -1e30f;
    pc = (e + 2 < deg) ? pc : -1e30f;
    pd = (e + 3 < deg) ? pd : -1e30f;
    float mn = fmaxf(m, fmaxf(fmaxf(pa, pb), fmaxf(pc, pd)));
    float sc = exp2f(m - mn);
    float wa = exp2f(pa - mn);
    float wb = exp2f(pb - mn);
    float wc = exp2f(pc - mn);
    float wd = exp2f(pd - mn);
    acc.x = fmaf(wd, xd0, fmaf(wc, xc0, fmaf(wb, xb0, fmaf(wa, xa0, acc.x * sc))));
    acc.y = fmaf(wd, xd1, fmaf(wc, xc1, fmaf(wb, xb1, fmaf(wa, xa1, acc.y * sc))));
    acc.z = fmaf(wd, xd2, fmaf(wc, xc2, fmaf(wb, xb2, fmaf(wa, xa2, acc.z * sc))));
    acc.w = fmaf(wd, xd3, fmaf(wc, xc3, fmaf(wb, xb3, fmaf(wa, xa3, acc.w * sc))));
    l = fmaf(l, sc, wa + wb + wc + wd);
    m = mn;

    q0 = f0; q1 = f1; q2 = f2; q3 = f3;
  }
#undef EDGE

  float inv = 1.f / (l + 1e-16f);
  float4 b1v = *(const float4*)&b1[ch];
  float4 h;
  h.x = acc.x * inv + b1v.x; h.x = h.x > 0.f ? h.x : expm1f(h.x);
  h.y = acc.y * inv + b1v.y; h.y = h.y > 0.f ? h.y : expm1f(h.y);
  h.z = acc.z * inv + b1v.z; h.z = h.z > 0.f ? h.z : expm1f(h.z);
  h.w = acc.w * inv + b1v.w; h.w = h.w > 0.f ? h.w : expm1f(h.w);

  float4 u0 = *(const float4*)&W2l[ch * 3 + 0];
  float4 u1 = *(const float4*)&W2l[ch * 3 + 4];
  float4 u2 = *(const float4*)&W2l[ch * 3 + 8];
  float al0 = fmaf(h.w, u2.y, fmaf(h.z, u1.z, fmaf(h.y, u0.w, h.x * u0.x)));
  float al1 = fmaf(h.w, u2.z, fmaf(h.z, u1.w, fmaf(h.y, u1.x, h.x * u0.y)));
  float al2 = fmaf(h.w, u2.w, fmaf(h.z, u2.x, fmaf(h.y, u1.y, h.x * u0.z)));
  float4 v0 = *(const float4*)&W2r[ch * 3 + 0];
  float4 v1 = *(const float4*)&W2r[ch * 3 + 4];
  float4 v2 = *(const float4*)&W2r[ch * 3 + 8];
  float ar0 = fmaf(h.w, v2.y, fmaf(h.z, v1.z, fmaf(h.y, v0.w, h.x * v0.x)));
  float ar1 = fmaf(h.w, v2.z, fmaf(h.z, v1.w, fmaf(h.y, v1.x, h.x * v0.y)));
  float ar2 = fmaf(h.w, v2.w, fmaf(h.z, v2.x, fmaf(h.y, v1.y, h.x * v0.z)));
#pragma unroll
  for (int off = 1; off < 32; off <<= 1) {
    al0 += __shfl_xor(al0, off); al1 += __shfl_xor(al1, off);
    al2 += __shfl_xor(al2, off); ar0 += __shfl_xor(ar0, off);
    ar1 += __shfl_xor(ar1, off); ar2 += __shfl_xor(ar2, off);
  }
  if (sub == 0 && wid * 2 + (lane >> 5) < n) {
    *(float4*)&xl2[node * 4] = make_float4(al0, al1, al2, 0.f);
    *(float4*)&xr2[node * 4] = make_float4(ar0, ar1, ar2, 0.f);
  }
}

// ---------------------------------------------------------------------------
// fused layer-2 edge phase + mean-pool. FOUR lanes per node (16 nodes per
// wave); quad_perm rotate-merge x2. Pool pre-reduced in LDS.
__global__ __launch_bounds__(256) void k_fused2(const float* __restrict__ xl2,
                                                const float* __restrict__ xr2,
                                                const int* __restrict__ row_ptr,
                                                const int* __restrict__ csr_src,
                                                const float* __restrict__ att2,
                                                const float* __restrict__ b2,
                                                const int* __restrict__ batch,
                                                float* __restrict__ gsum,
                                                float* __restrict__ gcnt, int n) {
  __shared__ float ls[NGRAPH * 3];
  __shared__ float lc[NGRAPH];
  int t = threadIdx.x;
  for (int i = t; i < NGRAPH * 3; i += 256) ls[i] = 0.f;
  for (int i = t; i < NGRAPH; i += 256) lc[i] = 0.f;
  __syncthreads();

  int node = (blockIdx.x * 256 + t) >> 2;  // 64 nodes per block
  int lane = t & 3;
  if (node < n) {
    float4 xrv = *(const float4*)&xr2[node * 4];
    float c0 = att2[0] * LOG2E, c1 = att2[1] * LOG2E, c2 = att2[2] * LOG2E;
    int s0 = row_ptr[node], s1 = row_ptr[node + 1];
    float m = -1e30f, l = 0.f, a0 = 0.f, a1 = 0.f, a2 = 0.f;
    for (int slot = s0 + lane; slot < s1; slot += 4) {
      int s = csr_src[slot];
      float4 xlv = *(const float4*)&xl2[s * 4];
      float t0 = xlv.x + xrv.x; t0 = fmaxf(t0, 0.2f * t0);
      float t1 = xlv.y + xrv.y; t1 = fmaxf(t1, 0.2f * t1);
      float t2 = xlv.z + xrv.z; t2 = fmaxf(t2, 0.2f * t2);
      float p = fmaf(t2, c2, fmaf(t1, c1, t0 * c0));
      float mn = fmaxf(m, p);
      float sc = exp2f(m - mn);
      float w  = exp2f(p - mn);
      a0 = a0 * sc + w * xlv.x;
      a1 = a1 * sc + w * xlv.y;
      a2 = a2 * sc + w * xlv.z;
      l = l * sc + w;
      m = mn;
    }
#define MERGEQ(C)                                                       \
    {                                                                   \
      float m2 = DPP_QUAD(C, m);                                        \
      float l2 = DPP_QUAD(C, l);                                        \
      float b0 = DPP_QUAD(C, a0);                                       \
      float b1v = DPP_QUAD(C, a1);                                      \
      float b2v = DPP_QUAD(C, a2);                                      \
      float mn = fmaxf(m, m2);                                          \
      float sA = exp2f(m - mn);                                         \
      float sB = exp2f(m2 - mn);                                        \
      a0 = a0 * sA + b0 * sB;                                           \
      a1 = a1 * sA + b1v * sB;                                          \
      a2 = a2 * sA + b2v * sB;                                          \
      l = l * sA + l2 * sB;                                             \
      m = mn;                                                           \
    }
    MERGEQ(0x39) MERGEQ(0x4E)
#undef MERGEQ
    if (lane == 0) {
      float inv = 1.f / (l + 1e-16f);
      float o0 = a0 * inv + b2[0];
      float o1 = a1 * inv + b2[1];
      float o2 = a2 * inv + b2[2];
      int b = batch[node];
      atomicAdd(&ls[b * 3 + 0], o0);
      atomicAdd(&ls[b * 3 + 1], o1);
      atomicAdd(&ls[b * 3 + 2], o2);
      atomicAdd(&lc[b], 1.f);
    }
  }
  __syncthreads();
  for (int i = t; i < NGRAPH * 3; i += 256)
    if (ls[i] != 0.f) atomicAdd(&gsum[i], ls[i]);
  for (int i = t; i < NGRAPH; i += 256)
    if (lc[i] != 0.f) atomicAdd(&gcnt[i], lc[i]);
}

// 1 block, 64 threads: per-graph mean + 2-layer MLP
__global__ __launch_bounds__(64) void k_mlp(const float* __restrict__ gsum,
                                            const float* __restrict__ gcnt,
                                            const float* __restrict__ Wr1,
                                            const float* __restrict__ br1,
                                            const float* __restrict__ Wr2,
                                            const float* __restrict__ br2,
                                            float* __restrict__ out) {
  int t = threadIdx.x;
  if (t >= NGRAPH) return;
  float cnt = fmaxf(gcnt[t], 1.f);
  float g0 = gsum[t * 3 + 0] / cnt;
  float g1 = gsum[t * 3 + 1] / cnt;
  float g2 = gsum[t * 3 + 2] / cnt;
  float o0 = br2[0], o1 = br2[1], o2 = br2[2];
  for (int j = 0; j < 64; ++j) {
    float hj = g0 * Wr1[j] + g1 * Wr1[64 + j] + g2 * Wr1[128 + j] + br1[j];
    hj = fmaxf(hj, 0.f);
    o0 = fmaf(hj, Wr2[j * 3 + 0], o0);
    o1 = fmaf(hj, Wr2[j * 3 + 1], o1);
    o2 = fmaf(hj, Wr2[j * 3 + 2], o2);
  }
  out[t * 3 + 0] = o0;
  out[t * 3 + 1] = o1;
  out[t * 3 + 2] = o2;
}

// ---------------------------------------------------------------------------
extern "C" void kernel_launch(void* const* d_in, const int* in_sizes, int n_in,
                              void* d_out, int out_size, void* d_ws, size_t ws_size,
                              hipStream_t stream) {
  const float* x    = (const float*)d_in[0];
  const int*   ei   = (const int*)d_in[1];
  const int*   batch= (const int*)d_in[2];
  const float* W1l  = (const float*)d_in[3];
  const float* W1r  = (const float*)d_in[4];
  const float* att1 = (const float*)d_in[5];
  const float* b1   = (const float*)d_in[6];
  const float* W2l  = (const float*)d_in[7];
  const float* W2r  = (const float*)d_in[8];
  const float* att2 = (const float*)d_in[9];
  const float* b2   = (const float*)d_in[10];
  const float* Wr1  = (const float*)d_in[11];
  const float* br1  = (const float*)d_in[12];
  const float* Wr2  = (const float*)d_in[13];
  const float* br2  = (const float*)d_in[14];
  float* out = (float*)d_out;

  const int N  = in_sizes[0] / 128;
  const int E  = in_sizes[1] / 2;
  const int Et = E + N;
  const int NB = (N + 1023) / 1024;    // scan blocks (<=64)
  const int NB32 = (N + 31) / 32;      // gmfma blocks
  const int DEGB = (Et + 255) / 256;   // deg/fill blocks

  char* p = (char*)d_ws;
  auto alloc = [&](size_t bytes) -> char* {
    char* r = p;
    p += (bytes + 255) & ~(size_t)255;
    return r;
  };
  unsigned short* xl1 = (unsigned short*)alloc((size_t)N * 128 * 2);  // f16
  unsigned short* xr1 = (unsigned short*)alloc((size_t)N * 128 * 2);  // f16
  int*      row_ptr= (int*)alloc((size_t)(N + 1) * 4);
  int*      csr_src= (int*)alloc((size_t)Et * 4);
  int*      rank   = (int*)alloc((size_t)Et * 4);
  int*      bsum   = (int*)alloc(64 * 4);
  // zero-init group (one memset): deg | gsum | gcnt
  char*     z0     = p;
  int*      deg    = (int*)alloc((size_t)N * 4);
  float*    gsum   = (float*)alloc(NGRAPH * 3 * 4);
  float*    gcnt   = (float*)alloc(NGRAPH * 4);
  size_t    zbytes = (size_t)(p - z0);
  float*    xl2    = (float*)alloc((size_t)N * 4 * 4);
  float*    xr2    = (float*)alloc((size_t)N * 4 * 4);
  unsigned short* whp = (unsigned short*)alloc((size_t)16 * 2048 * 2);
  unsigned short* wlp = (unsigned short*)alloc((size_t)16 * 2048 * 2);

  hipMemsetAsync(z0, 0, zbytes, stream);
  hipLaunchKernelGGL(k_prep, dim3(DEGB + 16), dim3(256), 0, stream,
                     ei, E, Et, deg, rank, W1l, W1r, whp, wlp, DEGB);
  hipLaunchKernelGGL(k_scan_part, dim3(NB), dim3(256), 0, stream, deg, bsum, N);
  hipLaunchKernelGGL(k_scan_write, dim3(NB), dim3(256), 0, stream,
                     deg, bsum, row_ptr, N, NB);
  hipLaunchKernelGGL(k_gmfill, dim3(NB32 + DEGB), dim3(256), 0, stream,
                     x, whp, wlp, xl1, xr1, N, NB32,
                     ei, E, Et, row_ptr, rank, csr_src);
  int waves1 = (N + 1) / 2;
  hipLaunchKernelGGL(k_fused1, dim3((waves1 * 64 + 255) / 256), dim3(256), 0, stream,
                     xl1, xr1, row_ptr, csr_src, att1, b1, W2l, W2r, xl2, xr2, N);
  hipLaunchKernelGGL(k_fused2, dim3((N * 4 + 255) / 256), dim3(256), 0, stream,
                     xl2, xr2, row_ptr, csr_src, att2, b2, batch, gsum, gcnt, N);
  hipLaunchKernelGGL(k_mlp, dim3(1), dim3(64), 0, stream,
                     gsum, gcnt, Wr1, br1, Wr2, br2, out);
}